// Round 4
// baseline (1152.644 us; speedup 1.0000x reference)
//
#include <hip/hip_runtime.h>
#include <hip/hip_bf16.h>

#define NN 8192
#define HH 4096
#define GG 8
#define STR 128            // fixed stride for per-node edge lists (max deg ~57)

// ---------------------------------------------------------------------------
// bf16 helpers (packed 2x bf16 per u32; element 2q in low 16 bits)
// ---------------------------------------------------------------------------
__device__ inline unsigned bf16rne(float f) {
    unsigned u = __float_as_uint(f);
    unsigned r = 0x7fffu + ((u >> 16) & 1u);
    return (u + r) >> 16;
}
__device__ inline unsigned pack2(float lo, float hi) {
    return bf16rne(lo) | (bf16rne(hi) << 16);
}
__device__ inline void acc8(float* __restrict__ acc, uint4 v) {
    const unsigned* pu = reinterpret_cast<const unsigned*>(&v);
    #pragma unroll
    for (int q = 0; q < 4; ++q) {
        const unsigned u = pu[q];
        acc[2 * q]     += __uint_as_float(u << 16);
        acc[2 * q + 1] += __uint_as_float(u & 0xffff0000u);
    }
}
__device__ inline void unpack8(uint4 v, float* __restrict__ h) {
    const unsigned* pu = reinterpret_cast<const unsigned*>(&v);
    #pragma unroll
    for (int q = 0; q < 4; ++q) {
        const unsigned u = pu[q];
        h[2 * q]     = __uint_as_float(u << 16);
        h[2 * q + 1] = __uint_as_float(u & 0xffff0000u);
    }
}

// fp32 -> packed bf16; 8 elems per thread
__global__ __launch_bounds__(256) void k_cvt(const float* __restrict__ src,
                                             uint4* __restrict__ dst) {
    const size_t i = (size_t)blockIdx.x * 256 + threadIdx.x;
    const float4 a = reinterpret_cast<const float4*>(src)[2 * i];
    const float4 b = reinterpret_cast<const float4*>(src)[2 * i + 1];
    uint4 o;
    o.x = pack2(a.x, a.y);
    o.y = pack2(a.z, a.w);
    o.z = pack2(b.x, b.y);
    o.w = pack2(b.z, b.w);
    dst[i] = o;
}

// ---------------------------------------------------------------------------
// Single-pass graph build (reads x ONCE).
//   csrX[r][*] : cols c with x[r,c] != 0        (x-pattern, for x@W1)
//   csrA[r][*] : cols c with A[r,c] != 0        (x-pattern + forced diagonal)
//   cscA[c][*] : rows r with A[r,c] != 0
//   colfill[c] -> in-degree (GCN deg), degX[r], degA[r]
// Fixed stride STR; LDS counters for row-local lists, global atomics for CSC.
// ---------------------------------------------------------------------------
__global__ __launch_bounds__(256) void k_build(const float* __restrict__ x,
                                               unsigned* __restrict__ colfill,
                                               unsigned* __restrict__ degX,
                                               unsigned* __restrict__ degA,
                                               unsigned* __restrict__ csrX,
                                               unsigned* __restrict__ csrA,
                                               unsigned* __restrict__ cscA) {
    const int r = blockIdx.x;
    __shared__ unsigned px, pa;
    if (threadIdx.x == 0) { px = 0u; pa = 0u; }
    __syncthreads();
    const float4* xr = reinterpret_cast<const float4*>(x + (size_t)r * NN);
    #pragma unroll
    for (int i = 0; i < NN / (4 * 256); ++i) {
        const int c4 = i * 256 + threadIdx.x;
        float4 v = xr[c4];
        const float* vp = reinterpret_cast<const float*>(&v);
        #pragma unroll
        for (int k = 0; k < 4; ++k) {
            const int c = c4 * 4 + k;
            const bool nzx = (vp[k] != 0.0f);
            const bool nzA = nzx || (c == r);
            if (nzx) {
                unsigned p = atomicAdd(&px, 1u);
                if (p < STR) csrX[(size_t)r * STR + p] = (unsigned)c;
            }
            if (nzA) {
                unsigned p = atomicAdd(&pa, 1u);
                if (p < STR) csrA[(size_t)r * STR + p] = (unsigned)c;
                unsigned q = atomicAdd(&colfill[c], 1u);
                if (q < STR) cscA[(size_t)c * STR + q] = (unsigned)r;
            }
        }
    }
    __syncthreads();
    if (threadIdx.x == 0) { degX[r] = px; degA[r] = pa; }
}

// dinv = rsqrt(deg); batch counts
__global__ __launch_bounds__(256) void k_prep(const unsigned* __restrict__ colfill,
                                              const int* __restrict__ batch,
                                              float* __restrict__ dinv,
                                              unsigned* __restrict__ cnt) {
    const int i = blockIdx.x * 256 + threadIdx.x;
    dinv[i] = rsqrtf((float)colfill[i]);
    atomicAdd(&cnt[batch[i]], 1u);
}

// pooled adjacency: s[g][r] = dinv[r] * sum_{c in rowA(r), batch[c]==g} dinv[c]
// one thread per row, branch-free register bins
__global__ __launch_bounds__(256) void k_s(const unsigned* __restrict__ degA,
                                           const unsigned* __restrict__ csrA,
                                           const float* __restrict__ dinv,
                                           const int* __restrict__ batch,
                                           float* __restrict__ s) {
    const int r = blockIdx.x * 256 + threadIdx.x;
    unsigned deg = degA[r];
    if (deg > STR) deg = STR;
    float bins[GG];
    #pragma unroll
    for (int g = 0; g < GG; ++g) bins[g] = 0.0f;
    for (unsigned e = 0; e < deg; ++e) {
        const unsigned c = csrA[(size_t)r * STR + e];
        const float d = dinv[c];
        const int gb = batch[c];
        #pragma unroll
        for (int g = 0; g < GG; ++g) bins[g] += (gb == g) ? d : 0.0f;
    }
    const float dr = dinv[r];
    #pragma unroll
    for (int g = 0; g < GG; ++g) s[(size_t)g * NN + r] = dr * bins[g];
}

// ---------------------------------------------------------------------------
// SpMM1: Mh[r,:] = bf16( dinv[r] * sum_{c in csrX(r)} W1h[c,:] )
// One row per block; 512 thr cover full H (8 bf16 each); unroll x8.
// ---------------------------------------------------------------------------
__global__ __launch_bounds__(512) void k_spmm1(const uint4* __restrict__ W1h,
                                               const unsigned* __restrict__ degX,
                                               const unsigned* __restrict__ csrX,
                                               const float* __restrict__ dinv,
                                               uint4* __restrict__ Mh) {
    const int r = blockIdx.x;
    const int j = threadIdx.x;
    unsigned deg = degX[r];
    if (deg > STR) deg = STR;
    __shared__ unsigned eidx[STR];
    for (unsigned i = threadIdx.x; i < deg; i += 512) eidx[i] = csrX[(size_t)r * STR + i];
    __syncthreads();

    float acc[8];
    #pragma unroll
    for (int q = 0; q < 8; ++q) acc[q] = 0.0f;
    unsigned e = 0;
    for (; e + 8 <= deg; e += 8) {
        const uint4 v0 = W1h[(size_t)eidx[e + 0] * (HH / 8) + j];
        const uint4 v1 = W1h[(size_t)eidx[e + 1] * (HH / 8) + j];
        const uint4 v2 = W1h[(size_t)eidx[e + 2] * (HH / 8) + j];
        const uint4 v3 = W1h[(size_t)eidx[e + 3] * (HH / 8) + j];
        const uint4 v4 = W1h[(size_t)eidx[e + 4] * (HH / 8) + j];
        const uint4 v5 = W1h[(size_t)eidx[e + 5] * (HH / 8) + j];
        const uint4 v6 = W1h[(size_t)eidx[e + 6] * (HH / 8) + j];
        const uint4 v7 = W1h[(size_t)eidx[e + 7] * (HH / 8) + j];
        acc8(acc, v0); acc8(acc, v1); acc8(acc, v2); acc8(acc, v3);
        acc8(acc, v4); acc8(acc, v5); acc8(acc, v6); acc8(acc, v7);
    }
    for (; e < deg; ++e) acc8(acc, W1h[(size_t)eidx[e] * (HH / 8) + j]);

    const float dr = dinv[r];
    uint4 o;
    o.x = pack2(dr * acc[0], dr * acc[1]);
    o.y = pack2(dr * acc[2], dr * acc[3]);
    o.z = pack2(dr * acc[4], dr * acc[5]);
    o.w = pack2(dr * acc[6], dr * acc[7]);
    Mh[(size_t)r * (HH / 8) + j] = o;
}

// ---------------------------------------------------------------------------
// conv1: hB[c,:] = bf16( relu(dinv[c] * sum_{rn in cscA(c)} Mh[rn,:] + b1) )
// (Mh pre-scaled by dinv[rn].)  One column per block; 512 thr; unroll x8.
// ---------------------------------------------------------------------------
__global__ __launch_bounds__(512) void k_conv1(const uint4* __restrict__ Mh,
                                               const float* __restrict__ b1,
                                               const float* __restrict__ dinv,
                                               const unsigned* __restrict__ colfill,
                                               const unsigned* __restrict__ cscA,
                                               uint4* __restrict__ hB) {
    const int c = blockIdx.x;
    const int j = threadIdx.x;
    unsigned deg = colfill[c];
    if (deg > STR) deg = STR;
    __shared__ unsigned eidx[STR];
    for (unsigned i = threadIdx.x; i < deg; i += 512) eidx[i] = cscA[(size_t)c * STR + i];
    __syncthreads();

    float acc[8];
    #pragma unroll
    for (int q = 0; q < 8; ++q) acc[q] = 0.0f;
    unsigned e = 0;
    for (; e + 8 <= deg; e += 8) {
        const uint4 v0 = Mh[(size_t)eidx[e + 0] * (HH / 8) + j];
        const uint4 v1 = Mh[(size_t)eidx[e + 1] * (HH / 8) + j];
        const uint4 v2 = Mh[(size_t)eidx[e + 2] * (HH / 8) + j];
        const uint4 v3 = Mh[(size_t)eidx[e + 3] * (HH / 8) + j];
        const uint4 v4 = Mh[(size_t)eidx[e + 4] * (HH / 8) + j];
        const uint4 v5 = Mh[(size_t)eidx[e + 5] * (HH / 8) + j];
        const uint4 v6 = Mh[(size_t)eidx[e + 6] * (HH / 8) + j];
        const uint4 v7 = Mh[(size_t)eidx[e + 7] * (HH / 8) + j];
        acc8(acc, v0); acc8(acc, v1); acc8(acc, v2); acc8(acc, v3);
        acc8(acc, v4); acc8(acc, v5); acc8(acc, v6); acc8(acc, v7);
    }
    for (; e < deg; ++e) acc8(acc, Mh[(size_t)eidx[e] * (HH / 8) + j]);

    const float dc = dinv[c];
    float bv[8];
    {
        const float4 a = reinterpret_cast<const float4*>(b1)[2 * j];
        const float4 b = reinterpret_cast<const float4*>(b1)[2 * j + 1];
        bv[0] = a.x; bv[1] = a.y; bv[2] = a.z; bv[3] = a.w;
        bv[4] = b.x; bv[5] = b.y; bv[6] = b.z; bv[7] = b.w;
    }
    float h[8];
    #pragma unroll
    for (int q = 0; q < 8; ++q) h[q] = fmaxf(fmaf(dc, acc[q], bv[q]), 0.0f);
    uint4 o;
    o.x = pack2(h[0], h[1]);
    o.y = pack2(h[2], h[3]);
    o.z = pack2(h[4], h[5]);
    o.w = pack2(h[6], h[7]);
    hB[(size_t)c * (HH / 8) + j] = o;
}

// ---------------------------------------------------------------------------
// Pool: t[g,:] += sum_c s[g,c] * h[c,:]
// ---------------------------------------------------------------------------
#define PC 32
__global__ __launch_bounds__(256) void k_pool(const uint4* __restrict__ hB,
                                              const float* __restrict__ s,
                                              float* __restrict__ t) {
    const int j = blockIdx.x * 256 + threadIdx.x;
    const int c0 = blockIdx.y * PC;
    __shared__ float s_t[GG * PC];
    if (threadIdx.x < GG * PC) {
        const int g = threadIdx.x / PC;
        const int cc = threadIdx.x % PC;
        s_t[threadIdx.x] = s[(size_t)g * NN + c0 + cc];
    }
    __syncthreads();
    float tacc[GG][8];
    #pragma unroll
    for (int g = 0; g < GG; ++g)
        #pragma unroll
        for (int q = 0; q < 8; ++q) tacc[g][q] = 0.0f;
    for (int cc = 0; cc < PC; ++cc) {
        const uint4 v = hB[(size_t)(c0 + cc) * (HH / 8) + j];
        float hv[8];
        unpack8(v, hv);
        #pragma unroll
        for (int g = 0; g < GG; ++g) {
            const float sv = s_t[g * PC + cc];
            #pragma unroll
            for (int q = 0; q < 8; ++q) tacc[g][q] = fmaf(sv, hv[q], tacc[g][q]);
        }
    }
    #pragma unroll
    for (int g = 0; g < GG; ++g)
        #pragma unroll
        for (int q = 0; q < 8; ++q)
            atomicAdd(&t[g * HH + j * 8 + q], tacc[g][q]);
}

// out[g,n] = b2[n]
__global__ __launch_bounds__(256) void k_initout(const float* __restrict__ b2,
                                                 float* __restrict__ out) {
    const int i = blockIdx.x * 256 + threadIdx.x;
    if (i < GG * NN) out[i] = b2[i & (NN - 1)];
}

// Final: out[g, n] += sum_j (t[g,j]/cnt[g]) * W2[j, n]
__global__ __launch_bounds__(256) void k_final(const float* __restrict__ W2,
                                               const float* __restrict__ t,
                                               const unsigned* __restrict__ cnt,
                                               float* __restrict__ out) {
    __shared__ float tld[GG * 128];
    const int tj = threadIdx.x;
    const int j0 = blockIdx.y * 128;
    const int nbase = blockIdx.x * 1024;
    for (int i = threadIdx.x; i < GG * 128; i += 256) {
        const int g = i >> 7;
        const int jj = i & 127;
        unsigned c = cnt[g];
        if (c < 1u) c = 1u;
        tld[i] = t[(size_t)g * HH + j0 + jj] * (1.0f / (float)c);
    }
    __syncthreads();
    float4 acc[GG];
    #pragma unroll
    for (int g = 0; g < GG; ++g) acc[g] = make_float4(0.f, 0.f, 0.f, 0.f);
    for (int jj = 0; jj < 128; ++jj) {
        const int jv = j0 + jj;
        float4 w = reinterpret_cast<const float4*>(W2 + (size_t)jv * NN + nbase)[tj];
        #pragma unroll
        for (int g = 0; g < GG; ++g) {
            const float tv = tld[g * 128 + jj];
            acc[g].x = fmaf(tv, w.x, acc[g].x);
            acc[g].y = fmaf(tv, w.y, acc[g].y);
            acc[g].z = fmaf(tv, w.z, acc[g].z);
            acc[g].w = fmaf(tv, w.w, acc[g].w);
        }
    }
    #pragma unroll
    for (int g = 0; g < GG; ++g) {
        const size_t base = (size_t)g * NN + nbase + tj * 4;
        atomicAdd(&out[base + 0], acc[g].x);
        atomicAdd(&out[base + 1], acc[g].y);
        atomicAdd(&out[base + 2], acc[g].z);
        atomicAdd(&out[base + 3], acc[g].w);
    }
}

extern "C" void kernel_launch(void* const* d_in, const int* in_sizes, int n_in,
                              void* d_out, int out_size, void* d_ws, size_t ws_size,
                              hipStream_t stream) {
    const float* x  = (const float*)d_in[0];
    const float* W1 = (const float*)d_in[1];
    const float* b1 = (const float*)d_in[2];
    const float* W2 = (const float*)d_in[3];
    const float* b2 = (const float*)d_in[4];
    const int* batch = (const int*)d_in[5];
    float* out = (float*)d_out;

    char* ws = (char*)d_ws;
    size_t off = 0;
    auto alloc = [&](size_t bytes) -> char* {
        char* p = ws + off;
        off = (off + bytes + 255) & ~(size_t)255;
        return p;
    };
    uint4*    Mh      = (uint4*)   alloc((size_t)NN * HH * 2);   // bf16 M (dinv-scaled)
    uint4*    W1h     = (uint4*)   alloc((size_t)NN * HH * 2);   // bf16 W1; REUSED as hB
    uint4*    hB      = W1h;   // h overlays W1h (dead after k_spmm1; stream-serial)
    char*     zbegin  = ws + off;
    float*    t       = (float*)   alloc((size_t)GG * HH * 4);
    unsigned* colfill = (unsigned*)alloc((size_t)NN * 4);
    unsigned* cnt     = (unsigned*)alloc((size_t)GG * 4);
    char*     zend    = ws + off;
    float*    s       = (float*)   alloc((size_t)GG * NN * 4);
    float*    dinv    = (float*)   alloc((size_t)NN * 4);
    unsigned* degX    = (unsigned*)alloc((size_t)NN * 4);
    unsigned* degA    = (unsigned*)alloc((size_t)NN * 4);
    unsigned* csrX    = (unsigned*)alloc((size_t)NN * STR * 4);
    unsigned* csrA    = (unsigned*)alloc((size_t)NN * STR * 4);
    unsigned* cscA    = (unsigned*)alloc((size_t)NN * STR * 4);
    (void)ws_size; (void)in_sizes; (void)n_in; (void)out_size;

    hipMemsetAsync(zbegin, 0, (size_t)(zend - zbegin), stream);

    k_cvt<<<(NN * HH / 8) / 256, 256, 0, stream>>>(W1, (uint4*)W1h);
    k_build<<<NN, 256, 0, stream>>>(x, colfill, degX, degA, csrX, csrA, cscA);
    k_prep<<<NN / 256, 256, 0, stream>>>(colfill, batch, dinv, cnt);
    k_s<<<NN / 256, 256, 0, stream>>>(degA, csrA, dinv, batch, s);
    k_spmm1<<<NN, 512, 0, stream>>>(W1h, degX, csrX, dinv, Mh);
    k_conv1<<<NN, 512, 0, stream>>>(Mh, b1, dinv, colfill, cscA, hB);
    k_pool<<<dim3(HH / 2048, NN / PC), 256, 0, stream>>>(hB, s, t);
    k_initout<<<(GG * NN) / 256, 256, 0, stream>>>(b2, out);
    k_final<<<dim3(NN / 1024, HH / 128), 256, 0, stream>>>(W2, t, cnt, out);
}

// Round 5
// 864.262 us; speedup vs baseline: 1.3337x; 1.3337x over previous
//
#include <hip/hip_runtime.h>
#include <hip/hip_bf16.h>

#define NN 8192
#define HH 4096
#define GG 8
#define STR 128            // fixed stride for per-node edge lists (max deg ~57)
#define NCH 32             // H chunks
#define CHU 16             // uint4 per chunk (= 128 cols = 256 B/row -> 2 MB/chunk)

// ---------------------------------------------------------------------------
// bf16 helpers (packed 2x bf16 per u32; element 2q in low 16 bits)
// ---------------------------------------------------------------------------
__device__ inline unsigned bf16rne(float f) {
    unsigned u = __float_as_uint(f);
    unsigned r = 0x7fffu + ((u >> 16) & 1u);
    return (u + r) >> 16;
}
__device__ inline unsigned pack2(float lo, float hi) {
    return bf16rne(lo) | (bf16rne(hi) << 16);
}
__device__ inline void acc8(float* __restrict__ acc, uint4 v) {
    const unsigned* pu = reinterpret_cast<const unsigned*>(&v);
    #pragma unroll
    for (int q = 0; q < 4; ++q) {
        const unsigned u = pu[q];
        acc[2 * q]     += __uint_as_float(u << 16);
        acc[2 * q + 1] += __uint_as_float(u & 0xffff0000u);
    }
}
__device__ inline void unpack8(uint4 v, float* __restrict__ h) {
    const unsigned* pu = reinterpret_cast<const unsigned*>(&v);
    #pragma unroll
    for (int q = 0; q < 4; ++q) {
        const unsigned u = pu[q];
        h[2 * q]     = __uint_as_float(u << 16);
        h[2 * q + 1] = __uint_as_float(u & 0xffff0000u);
    }
}

// fp32 -> packed bf16; 8 elems per thread
__global__ __launch_bounds__(256) void k_cvt(const float* __restrict__ src,
                                             uint4* __restrict__ dst) {
    const size_t i = (size_t)blockIdx.x * 256 + threadIdx.x;
    const float4 a = reinterpret_cast<const float4*>(src)[2 * i];
    const float4 b = reinterpret_cast<const float4*>(src)[2 * i + 1];
    uint4 o;
    o.x = pack2(a.x, a.y);
    o.y = pack2(a.z, a.w);
    o.z = pack2(b.x, b.y);
    o.w = pack2(b.z, b.w);
    dst[i] = o;
}

// ---------------------------------------------------------------------------
// Single-pass graph build (reads x ONCE).
// ---------------------------------------------------------------------------
__global__ __launch_bounds__(256) void k_build(const float* __restrict__ x,
                                               unsigned* __restrict__ colfill,
                                               unsigned* __restrict__ degX,
                                               unsigned* __restrict__ degA,
                                               unsigned* __restrict__ csrX,
                                               unsigned* __restrict__ csrA,
                                               unsigned* __restrict__ cscA) {
    const int r = blockIdx.x;
    __shared__ unsigned px, pa;
    if (threadIdx.x == 0) { px = 0u; pa = 0u; }
    __syncthreads();
    const float4* xr = reinterpret_cast<const float4*>(x + (size_t)r * NN);
    #pragma unroll
    for (int i = 0; i < NN / (4 * 256); ++i) {
        const int c4 = i * 256 + threadIdx.x;
        float4 v = xr[c4];
        const float* vp = reinterpret_cast<const float*>(&v);
        #pragma unroll
        for (int k = 0; k < 4; ++k) {
            const int c = c4 * 4 + k;
            const bool nzx = (vp[k] != 0.0f);
            const bool nzA = nzx || (c == r);
            if (nzx) {
                unsigned p = atomicAdd(&px, 1u);
                if (p < STR) csrX[(size_t)r * STR + p] = (unsigned)c;
            }
            if (nzA) {
                unsigned p = atomicAdd(&pa, 1u);
                if (p < STR) csrA[(size_t)r * STR + p] = (unsigned)c;
                unsigned q = atomicAdd(&colfill[c], 1u);
                if (q < STR) cscA[(size_t)c * STR + q] = (unsigned)r;
            }
        }
    }
    __syncthreads();
    if (threadIdx.x == 0) { degX[r] = px; degA[r] = pa; }
}

// dinv = rsqrt(deg); batch counts
__global__ __launch_bounds__(256) void k_prep(const unsigned* __restrict__ colfill,
                                              const int* __restrict__ batch,
                                              float* __restrict__ dinv,
                                              unsigned* __restrict__ cnt) {
    const int i = blockIdx.x * 256 + threadIdx.x;
    dinv[i] = rsqrtf((float)colfill[i]);
    atomicAdd(&cnt[batch[i]], 1u);
}

// pooled adjacency: s[g][r] = dinv[r] * sum_{c in rowA(r), batch[c]==g} dinv[c]
__global__ __launch_bounds__(256) void k_s(const unsigned* __restrict__ degA,
                                           const unsigned* __restrict__ csrA,
                                           const float* __restrict__ dinv,
                                           const int* __restrict__ batch,
                                           float* __restrict__ s) {
    const int r = blockIdx.x * 256 + threadIdx.x;
    unsigned deg = degA[r];
    if (deg > STR) deg = STR;
    float bins[GG];
    #pragma unroll
    for (int g = 0; g < GG; ++g) bins[g] = 0.0f;
    for (unsigned e = 0; e < deg; ++e) {
        const unsigned c = csrA[(size_t)r * STR + e];
        const float d = dinv[c];
        const int gb = batch[c];
        #pragma unroll
        for (int g = 0; g < GG; ++g) bins[g] += (gb == g) ? d : 0.0f;
    }
    const float dr = dinv[r];
    #pragma unroll
    for (int g = 0; g < GG; ++g) s[(size_t)g * NN + r] = dr * bins[g];
}

// ---------------------------------------------------------------------------
// Chunked SpMM1: per (node-pair, chunk) block. Wave w handles node 2*bx+w.
// Within a wave: 4 edge slots x 16 lanes x 8 bf16 = 128-col chunk.
// Mh[r, ch] = bf16( dinv[r] * sum_{c in csrX(r)} W1h[c, ch] )
// ---------------------------------------------------------------------------
__global__ __launch_bounds__(128) void k_spmm1(const uint4* __restrict__ W1h,
                                               const unsigned* __restrict__ degX,
                                               const unsigned* __restrict__ csrX,
                                               const float* __restrict__ dinv,
                                               uint4* __restrict__ Mh) {
    const int wid  = threadIdx.x >> 6;
    const int lane = threadIdx.x & 63;
    const int node = blockIdx.x * 2 + wid;
    const int ch   = blockIdx.y;
    const int sub  = lane >> 4;
    const int l16  = lane & 15;
    __shared__ unsigned eidx[2][STR];
    unsigned deg = degX[node];
    if (deg > STR) deg = STR;
    for (unsigned i = lane; i < deg; i += 64)
        eidx[wid][i] = csrX[(size_t)node * STR + i];
    __syncthreads();

    const uint4* src = W1h + (size_t)ch * CHU + l16;
    float acc[8];
    #pragma unroll
    for (int q = 0; q < 8; ++q) acc[q] = 0.0f;
    unsigned e = sub;
    for (; e + 4 < deg; e += 8) {
        const uint4 va = src[(size_t)eidx[wid][e] * (HH / 8)];
        const uint4 vb = src[(size_t)eidx[wid][e + 4] * (HH / 8)];
        acc8(acc, va);
        acc8(acc, vb);
    }
    if (e < deg) acc8(acc, src[(size_t)eidx[wid][e] * (HH / 8)]);

    #pragma unroll
    for (int q = 0; q < 8; ++q) {
        acc[q] += __shfl_xor(acc[q], 16);
        acc[q] += __shfl_xor(acc[q], 32);
    }
    if (sub == 0) {
        const float dr = dinv[node];
        uint4 o;
        o.x = pack2(dr * acc[0], dr * acc[1]);
        o.y = pack2(dr * acc[2], dr * acc[3]);
        o.z = pack2(dr * acc[4], dr * acc[5]);
        o.w = pack2(dr * acc[6], dr * acc[7]);
        Mh[(size_t)node * (HH / 8) + ch * CHU + l16] = o;
    }
}

// ---------------------------------------------------------------------------
// Chunked conv1: hB[c, ch] = bf16( relu(dinv[c]*sum_{rn in cscA(c)} Mh[rn,ch] + b1) )
// (Mh pre-scaled by dinv[rn].)
// ---------------------------------------------------------------------------
__global__ __launch_bounds__(128) void k_conv1(const uint4* __restrict__ Mh,
                                               const float* __restrict__ b1,
                                               const float* __restrict__ dinv,
                                               const unsigned* __restrict__ colfill,
                                               const unsigned* __restrict__ cscA,
                                               uint4* __restrict__ hB) {
    const int wid  = threadIdx.x >> 6;
    const int lane = threadIdx.x & 63;
    const int node = blockIdx.x * 2 + wid;
    const int ch   = blockIdx.y;
    const int sub  = lane >> 4;
    const int l16  = lane & 15;
    __shared__ unsigned eidx[2][STR];
    unsigned deg = colfill[node];
    if (deg > STR) deg = STR;
    for (unsigned i = lane; i < deg; i += 64)
        eidx[wid][i] = cscA[(size_t)node * STR + i];
    __syncthreads();

    const uint4* src = Mh + (size_t)ch * CHU + l16;
    float acc[8];
    #pragma unroll
    for (int q = 0; q < 8; ++q) acc[q] = 0.0f;
    unsigned e = sub;
    for (; e + 4 < deg; e += 8) {
        const uint4 va = src[(size_t)eidx[wid][e] * (HH / 8)];
        const uint4 vb = src[(size_t)eidx[wid][e + 4] * (HH / 8)];
        acc8(acc, va);
        acc8(acc, vb);
    }
    if (e < deg) acc8(acc, src[(size_t)eidx[wid][e] * (HH / 8)]);

    #pragma unroll
    for (int q = 0; q < 8; ++q) {
        acc[q] += __shfl_xor(acc[q], 16);
        acc[q] += __shfl_xor(acc[q], 32);
    }
    if (sub == 0) {
        const float dc = dinv[node];
        const float4 ba = reinterpret_cast<const float4*>(b1)[ch * (CHU * 2) + l16 * 2];
        const float4 bb = reinterpret_cast<const float4*>(b1)[ch * (CHU * 2) + l16 * 2 + 1];
        float h[8];
        h[0] = fmaxf(fmaf(dc, acc[0], ba.x), 0.0f);
        h[1] = fmaxf(fmaf(dc, acc[1], ba.y), 0.0f);
        h[2] = fmaxf(fmaf(dc, acc[2], ba.z), 0.0f);
        h[3] = fmaxf(fmaf(dc, acc[3], ba.w), 0.0f);
        h[4] = fmaxf(fmaf(dc, acc[4], bb.x), 0.0f);
        h[5] = fmaxf(fmaf(dc, acc[5], bb.y), 0.0f);
        h[6] = fmaxf(fmaf(dc, acc[6], bb.z), 0.0f);
        h[7] = fmaxf(fmaf(dc, acc[7], bb.w), 0.0f);
        uint4 o;
        o.x = pack2(h[0], h[1]);
        o.y = pack2(h[2], h[3]);
        o.z = pack2(h[4], h[5]);
        o.w = pack2(h[6], h[7]);
        hB[(size_t)node * (HH / 8) + ch * CHU + l16] = o;
    }
}

// ---------------------------------------------------------------------------
// Pool: t[g,:] += sum_c s[g,c] * h[c,:]
// ---------------------------------------------------------------------------
#define PC 32
__global__ __launch_bounds__(256) void k_pool(const uint4* __restrict__ hB,
                                              const float* __restrict__ s,
                                              float* __restrict__ t) {
    const int j = blockIdx.x * 256 + threadIdx.x;
    const int c0 = blockIdx.y * PC;
    __shared__ float s_t[GG * PC];
    if (threadIdx.x < GG * PC) {
        const int g = threadIdx.x / PC;
        const int cc = threadIdx.x % PC;
        s_t[threadIdx.x] = s[(size_t)g * NN + c0 + cc];
    }
    __syncthreads();
    float tacc[GG][8];
    #pragma unroll
    for (int g = 0; g < GG; ++g)
        #pragma unroll
        for (int q = 0; q < 8; ++q) tacc[g][q] = 0.0f;
    for (int cc = 0; cc < PC; ++cc) {
        const uint4 v = hB[(size_t)(c0 + cc) * (HH / 8) + j];
        float hv[8];
        unpack8(v, hv);
        #pragma unroll
        for (int g = 0; g < GG; ++g) {
            const float sv = s_t[g * PC + cc];
            #pragma unroll
            for (int q = 0; q < 8; ++q) tacc[g][q] = fmaf(sv, hv[q], tacc[g][q]);
        }
    }
    #pragma unroll
    for (int g = 0; g < GG; ++g)
        #pragma unroll
        for (int q = 0; q < 8; ++q)
            atomicAdd(&t[g * HH + j * 8 + q], tacc[g][q]);
}

// out[g,n] = b2[n]
__global__ __launch_bounds__(256) void k_initout(const float* __restrict__ b2,
                                                 float* __restrict__ out) {
    const int i = blockIdx.x * 256 + threadIdx.x;
    if (i < GG * NN) out[i] = b2[i & (NN - 1)];
}

// Final: out[g, n] += sum_j (t[g,j]/cnt[g]) * W2[j, n]
__global__ __launch_bounds__(256) void k_final(const float* __restrict__ W2,
                                               const float* __restrict__ t,
                                               const unsigned* __restrict__ cnt,
                                               float* __restrict__ out) {
    __shared__ float tld[GG * 128];
    const int tj = threadIdx.x;
    const int j0 = blockIdx.y * 128;
    const int nbase = blockIdx.x * 1024;
    for (int i = threadIdx.x; i < GG * 128; i += 256) {
        const int g = i >> 7;
        const int jj = i & 127;
        unsigned c = cnt[g];
        if (c < 1u) c = 1u;
        tld[i] = t[(size_t)g * HH + j0 + jj] * (1.0f / (float)c);
    }
    __syncthreads();
    float4 acc[GG];
    #pragma unroll
    for (int g = 0; g < GG; ++g) acc[g] = make_float4(0.f, 0.f, 0.f, 0.f);
    for (int jj = 0; jj < 128; ++jj) {
        const int jv = j0 + jj;
        float4 w = reinterpret_cast<const float4*>(W2 + (size_t)jv * NN + nbase)[tj];
        #pragma unroll
        for (int g = 0; g < GG; ++g) {
            const float tv = tld[g * 128 + jj];
            acc[g].x = fmaf(tv, w.x, acc[g].x);
            acc[g].y = fmaf(tv, w.y, acc[g].y);
            acc[g].z = fmaf(tv, w.z, acc[g].z);
            acc[g].w = fmaf(tv, w.w, acc[g].w);
        }
    }
    #pragma unroll
    for (int g = 0; g < GG; ++g) {
        const size_t base = (size_t)g * NN + nbase + tj * 4;
        atomicAdd(&out[base + 0], acc[g].x);
        atomicAdd(&out[base + 1], acc[g].y);
        atomicAdd(&out[base + 2], acc[g].z);
        atomicAdd(&out[base + 3], acc[g].w);
    }
}

extern "C" void kernel_launch(void* const* d_in, const int* in_sizes, int n_in,
                              void* d_out, int out_size, void* d_ws, size_t ws_size,
                              hipStream_t stream) {
    const float* x  = (const float*)d_in[0];
    const float* W1 = (const float*)d_in[1];
    const float* b1 = (const float*)d_in[2];
    const float* W2 = (const float*)d_in[3];
    const float* b2 = (const float*)d_in[4];
    const int* batch = (const int*)d_in[5];
    float* out = (float*)d_out;

    char* ws = (char*)d_ws;
    size_t off = 0;
    auto alloc = [&](size_t bytes) -> char* {
        char* p = ws + off;
        off = (off + bytes + 255) & ~(size_t)255;
        return p;
    };
    uint4*    Mh      = (uint4*)   alloc((size_t)NN * HH * 2);   // bf16 M (dinv-scaled)
    uint4*    W1h     = (uint4*)   alloc((size_t)NN * HH * 2);   // bf16 W1; REUSED as hB
    uint4*    hB      = W1h;   // h overlays W1h (dead after k_spmm1; stream-serial)
    char*     zbegin  = ws + off;
    float*    t       = (float*)   alloc((size_t)GG * HH * 4);
    unsigned* colfill = (unsigned*)alloc((size_t)NN * 4);
    unsigned* cnt     = (unsigned*)alloc((size_t)GG * 4);
    char*     zend    = ws + off;
    float*    s       = (float*)   alloc((size_t)GG * NN * 4);
    float*    dinv    = (float*)   alloc((size_t)NN * 4);
    unsigned* degX    = (unsigned*)alloc((size_t)NN * 4);
    unsigned* degA    = (unsigned*)alloc((size_t)NN * 4);
    unsigned* csrX    = (unsigned*)alloc((size_t)NN * STR * 4);
    unsigned* csrA    = (unsigned*)alloc((size_t)NN * STR * 4);
    unsigned* cscA    = (unsigned*)alloc((size_t)NN * STR * 4);
    (void)ws_size; (void)in_sizes; (void)n_in; (void)out_size;

    hipMemsetAsync(zbegin, 0, (size_t)(zend - zbegin), stream);

    k_cvt<<<(NN * HH / 8) / 256, 256, 0, stream>>>(W1, (uint4*)W1h);
    k_build<<<NN, 256, 0, stream>>>(x, colfill, degX, degA, csrX, csrA, cscA);
    k_prep<<<NN / 256, 256, 0, stream>>>(colfill, batch, dinv, cnt);
    k_s<<<NN / 256, 256, 0, stream>>>(degA, csrA, dinv, batch, s);
    k_spmm1<<<dim3(NN / 2, NCH), 128, 0, stream>>>(W1h, degX, csrX, dinv, Mh);
    k_conv1<<<dim3(NN / 2, NCH), 128, 0, stream>>>(Mh, b1, dinv, colfill, cscA, hB);
    k_pool<<<dim3(HH / 2048, NN / PC), 256, 0, stream>>>(hB, s, t);
    k_initout<<<(GG * NN) / 256, 256, 0, stream>>>(b2, out);
    k_final<<<dim3(NN / 1024, HH / 128), 256, 0, stream>>>(W2, t, cnt, out);
}

// Round 6
// 639.375 us; speedup vs baseline: 1.8028x; 1.3517x over previous
//
#include <hip/hip_runtime.h>
#include <hip/hip_bf16.h>

#define NN 8192
#define HH 4096
#define GG 8
#define STR 128            // fixed stride for per-node edge lists (max deg ~57)
#define NCH 32             // H chunks
#define CHU 16             // uint4 per chunk (= 128 cols = 256 B/row -> 2 MB/chunk)
#define PRG 64             // pool row-groups (partial-reduction factor)
#define FJG 32             // final j-groups

// ---------------------------------------------------------------------------
// bf16 helpers (packed 2x bf16 per u32; element 2q in low 16 bits)
// ---------------------------------------------------------------------------
__device__ inline unsigned bf16rne(float f) {
    unsigned u = __float_as_uint(f);
    unsigned r = 0x7fffu + ((u >> 16) & 1u);
    return (u + r) >> 16;
}
__device__ inline unsigned pack2(float lo, float hi) {
    return bf16rne(lo) | (bf16rne(hi) << 16);
}
__device__ inline void acc8(float* __restrict__ acc, uint4 v) {
    const unsigned* pu = reinterpret_cast<const unsigned*>(&v);
    #pragma unroll
    for (int q = 0; q < 4; ++q) {
        const unsigned u = pu[q];
        acc[2 * q]     += __uint_as_float(u << 16);
        acc[2 * q + 1] += __uint_as_float(u & 0xffff0000u);
    }
}
__device__ inline void unpack8(uint4 v, float* __restrict__ h) {
    const unsigned* pu = reinterpret_cast<const unsigned*>(&v);
    #pragma unroll
    for (int q = 0; q < 4; ++q) {
        const unsigned u = pu[q];
        h[2 * q]     = __uint_as_float(u << 16);
        h[2 * q + 1] = __uint_as_float(u & 0xffff0000u);
    }
}

// fp32 -> packed bf16; 8 elems per thread
__global__ __launch_bounds__(256) void k_cvt(const float* __restrict__ src,
                                             uint4* __restrict__ dst) {
    const size_t i = (size_t)blockIdx.x * 256 + threadIdx.x;
    const float4 a = reinterpret_cast<const float4*>(src)[2 * i];
    const float4 b = reinterpret_cast<const float4*>(src)[2 * i + 1];
    uint4 o;
    o.x = pack2(a.x, a.y);
    o.y = pack2(a.z, a.w);
    o.z = pack2(b.x, b.y);
    o.w = pack2(b.z, b.w);
    dst[i] = o;
}

// ---------------------------------------------------------------------------
// Single-pass graph build (reads x ONCE).
// ---------------------------------------------------------------------------
__global__ __launch_bounds__(256) void k_build(const float* __restrict__ x,
                                               unsigned* __restrict__ colfill,
                                               unsigned* __restrict__ degX,
                                               unsigned* __restrict__ degA,
                                               unsigned* __restrict__ csrX,
                                               unsigned* __restrict__ csrA,
                                               unsigned* __restrict__ cscA) {
    const int r = blockIdx.x;
    __shared__ unsigned px, pa;
    if (threadIdx.x == 0) { px = 0u; pa = 0u; }
    __syncthreads();
    const float4* xr = reinterpret_cast<const float4*>(x + (size_t)r * NN);
    #pragma unroll
    for (int i = 0; i < NN / (4 * 256); ++i) {
        const int c4 = i * 256 + threadIdx.x;
        float4 v = xr[c4];
        const float* vp = reinterpret_cast<const float*>(&v);
        #pragma unroll
        for (int k = 0; k < 4; ++k) {
            const int c = c4 * 4 + k;
            const bool nzx = (vp[k] != 0.0f);
            const bool nzA = nzx || (c == r);
            if (nzx) {
                unsigned p = atomicAdd(&px, 1u);
                if (p < STR) csrX[(size_t)r * STR + p] = (unsigned)c;
            }
            if (nzA) {
                unsigned p = atomicAdd(&pa, 1u);
                if (p < STR) csrA[(size_t)r * STR + p] = (unsigned)c;
                unsigned q = atomicAdd(&colfill[c], 1u);
                if (q < STR) cscA[(size_t)c * STR + q] = (unsigned)r;
            }
        }
    }
    __syncthreads();
    if (threadIdx.x == 0) { degX[r] = px; degA[r] = pa; }
}

// dinv = rsqrt(deg); batch counts
__global__ __launch_bounds__(256) void k_prep(const unsigned* __restrict__ colfill,
                                              const int* __restrict__ batch,
                                              float* __restrict__ dinv,
                                              unsigned* __restrict__ cnt) {
    const int i = blockIdx.x * 256 + threadIdx.x;
    dinv[i] = rsqrtf((float)colfill[i]);
    atomicAdd(&cnt[batch[i]], 1u);
}

// pooled adjacency: s[g][r] = dinv[r] * sum_{c in rowA(r), batch[c]==g} dinv[c]
__global__ __launch_bounds__(256) void k_s(const unsigned* __restrict__ degA,
                                           const unsigned* __restrict__ csrA,
                                           const float* __restrict__ dinv,
                                           const int* __restrict__ batch,
                                           float* __restrict__ s) {
    const int r = blockIdx.x * 256 + threadIdx.x;
    unsigned deg = degA[r];
    if (deg > STR) deg = STR;
    float bins[GG];
    #pragma unroll
    for (int g = 0; g < GG; ++g) bins[g] = 0.0f;
    for (unsigned e = 0; e < deg; ++e) {
        const unsigned c = csrA[(size_t)r * STR + e];
        const float d = dinv[c];
        const int gb = batch[c];
        #pragma unroll
        for (int g = 0; g < GG; ++g) bins[g] += (gb == g) ? d : 0.0f;
    }
    const float dr = dinv[r];
    #pragma unroll
    for (int g = 0; g < GG; ++g) s[(size_t)g * NN + r] = dr * bins[g];
}

// ---------------------------------------------------------------------------
// Chunked SpMM1: per (node-pair, chunk) block. Wave w handles node 2*bx+w.
// Within a wave: 4 edge slots x 16 lanes x 8 bf16 = 128-col chunk.
// Mh[r, ch] = bf16( dinv[r] * sum_{c in csrX(r)} W1h[c, ch] )
// ---------------------------------------------------------------------------
__global__ __launch_bounds__(128) void k_spmm1(const uint4* __restrict__ W1h,
                                               const unsigned* __restrict__ degX,
                                               const unsigned* __restrict__ csrX,
                                               const float* __restrict__ dinv,
                                               uint4* __restrict__ Mh) {
    const int wid  = threadIdx.x >> 6;
    const int lane = threadIdx.x & 63;
    const int node = blockIdx.x * 2 + wid;
    const int ch   = blockIdx.y;
    const int sub  = lane >> 4;
    const int l16  = lane & 15;
    __shared__ unsigned eidx[2][STR];
    unsigned deg = degX[node];
    if (deg > STR) deg = STR;
    for (unsigned i = lane; i < deg; i += 64)
        eidx[wid][i] = csrX[(size_t)node * STR + i];
    __syncthreads();

    const uint4* src = W1h + (size_t)ch * CHU + l16;
    float acc[8];
    #pragma unroll
    for (int q = 0; q < 8; ++q) acc[q] = 0.0f;
    unsigned e = sub;
    for (; e + 4 < deg; e += 8) {
        const uint4 va = src[(size_t)eidx[wid][e] * (HH / 8)];
        const uint4 vb = src[(size_t)eidx[wid][e + 4] * (HH / 8)];
        acc8(acc, va);
        acc8(acc, vb);
    }
    if (e < deg) acc8(acc, src[(size_t)eidx[wid][e] * (HH / 8)]);

    #pragma unroll
    for (int q = 0; q < 8; ++q) {
        acc[q] += __shfl_xor(acc[q], 16);
        acc[q] += __shfl_xor(acc[q], 32);
    }
    if (sub == 0) {
        const float dr = dinv[node];
        uint4 o;
        o.x = pack2(dr * acc[0], dr * acc[1]);
        o.y = pack2(dr * acc[2], dr * acc[3]);
        o.z = pack2(dr * acc[4], dr * acc[5]);
        o.w = pack2(dr * acc[6], dr * acc[7]);
        Mh[(size_t)node * (HH / 8) + ch * CHU + l16] = o;
    }
}

// ---------------------------------------------------------------------------
// Chunked conv1: hB[c, ch] = bf16( relu(dinv[c]*sum_{rn in cscA(c)} Mh[rn,ch] + b1) )
// (Mh pre-scaled by dinv[rn].)
// ---------------------------------------------------------------------------
__global__ __launch_bounds__(128) void k_conv1(const uint4* __restrict__ Mh,
                                               const float* __restrict__ b1,
                                               const float* __restrict__ dinv,
                                               const unsigned* __restrict__ colfill,
                                               const unsigned* __restrict__ cscA,
                                               uint4* __restrict__ hB) {
    const int wid  = threadIdx.x >> 6;
    const int lane = threadIdx.x & 63;
    const int node = blockIdx.x * 2 + wid;
    const int ch   = blockIdx.y;
    const int sub  = lane >> 4;
    const int l16  = lane & 15;
    __shared__ unsigned eidx[2][STR];
    unsigned deg = colfill[node];
    if (deg > STR) deg = STR;
    for (unsigned i = lane; i < deg; i += 64)
        eidx[wid][i] = cscA[(size_t)node * STR + i];
    __syncthreads();

    const uint4* src = Mh + (size_t)ch * CHU + l16;
    float acc[8];
    #pragma unroll
    for (int q = 0; q < 8; ++q) acc[q] = 0.0f;
    unsigned e = sub;
    for (; e + 4 < deg; e += 8) {
        const uint4 va = src[(size_t)eidx[wid][e] * (HH / 8)];
        const uint4 vb = src[(size_t)eidx[wid][e + 4] * (HH / 8)];
        acc8(acc, va);
        acc8(acc, vb);
    }
    if (e < deg) acc8(acc, src[(size_t)eidx[wid][e] * (HH / 8)]);

    #pragma unroll
    for (int q = 0; q < 8; ++q) {
        acc[q] += __shfl_xor(acc[q], 16);
        acc[q] += __shfl_xor(acc[q], 32);
    }
    if (sub == 0) {
        const float dc = dinv[node];
        const float4 ba = reinterpret_cast<const float4*>(b1)[ch * (CHU * 2) + l16 * 2];
        const float4 bb = reinterpret_cast<const float4*>(b1)[ch * (CHU * 2) + l16 * 2 + 1];
        float h[8];
        h[0] = fmaxf(fmaf(dc, acc[0], ba.x), 0.0f);
        h[1] = fmaxf(fmaf(dc, acc[1], ba.y), 0.0f);
        h[2] = fmaxf(fmaf(dc, acc[2], ba.z), 0.0f);
        h[3] = fmaxf(fmaf(dc, acc[3], ba.w), 0.0f);
        h[4] = fmaxf(fmaf(dc, acc[4], bb.x), 0.0f);
        h[5] = fmaxf(fmaf(dc, acc[5], bb.y), 0.0f);
        h[6] = fmaxf(fmaf(dc, acc[6], bb.z), 0.0f);
        h[7] = fmaxf(fmaf(dc, acc[7], bb.w), 0.0f);
        uint4 o;
        o.x = pack2(h[0], h[1]);
        o.y = pack2(h[2], h[3]);
        o.z = pack2(h[4], h[5]);
        o.w = pack2(h[6], h[7]);
        hB[(size_t)node * (HH / 8) + ch * CHU + l16] = o;
    }
}

// ---------------------------------------------------------------------------
// Pool stage A: partial t per row-group, NO atomics.
//   part[rg][g][:] = sum_{c in rowgroup rg} s[g,c] * h[c,:]
// grid (HH/2048, PRG); 256 thr x 8 elems; 128 rows per block.
// ---------------------------------------------------------------------------
__global__ __launch_bounds__(256) void k_poolA(const uint4* __restrict__ hB,
                                               const float* __restrict__ s,
                                               float* __restrict__ part) {
    const int j = blockIdx.x * 256 + threadIdx.x;      // uint4 col index
    const int c0 = blockIdx.y * (NN / PRG);            // 128 rows
    __shared__ float s_t[GG * (NN / PRG)];
    for (int i = threadIdx.x; i < GG * (NN / PRG); i += 256) {
        const int g = i / (NN / PRG);
        const int cc = i % (NN / PRG);
        s_t[i] = s[(size_t)g * NN + c0 + cc];
    }
    __syncthreads();
    float tacc[GG][8];
    #pragma unroll
    for (int g = 0; g < GG; ++g)
        #pragma unroll
        for (int q = 0; q < 8; ++q) tacc[g][q] = 0.0f;
    for (int cc = 0; cc < NN / PRG; ++cc) {
        const uint4 v = hB[(size_t)(c0 + cc) * (HH / 8) + j];
        float hv[8];
        unpack8(v, hv);
        #pragma unroll
        for (int g = 0; g < GG; ++g) {
            const float sv = s_t[g * (NN / PRG) + cc];
            #pragma unroll
            for (int q = 0; q < 8; ++q) tacc[g][q] = fmaf(sv, hv[q], tacc[g][q]);
        }
    }
    float4* p4 = reinterpret_cast<float4*>(part);
    #pragma unroll
    for (int g = 0; g < GG; ++g) {
        const size_t base = ((size_t)(blockIdx.y * GG + g) * HH) / 4 + j * 2;
        p4[base]     = make_float4(tacc[g][0], tacc[g][1], tacc[g][2], tacc[g][3]);
        p4[base + 1] = make_float4(tacc[g][4], tacc[g][5], tacc[g][6], tacc[g][7]);
    }
}

// Pool stage B: t[g][j] = sum_rg part[rg][g][j]
__global__ __launch_bounds__(256) void k_poolB(const float* __restrict__ part,
                                               float* __restrict__ t) {
    const int idx = blockIdx.x * 256 + threadIdx.x;    // float4 index into t
    const int g = idx / (HH / 4);
    const int j4 = idx % (HH / 4);
    const float4* p4 = reinterpret_cast<const float4*>(part);
    float4 acc = make_float4(0.f, 0.f, 0.f, 0.f);
    for (int rg = 0; rg < PRG; ++rg) {
        const float4 v = p4[((size_t)(rg * GG + g) * HH) / 4 + j4];
        acc.x += v.x; acc.y += v.y; acc.z += v.z; acc.w += v.w;
    }
    reinterpret_cast<float4*>(t)[idx] = acc;
}

// ---------------------------------------------------------------------------
// Final stage A: part2[jg][g][n] = sum_{j in jgroup} (t[g,j]/cnt[g]) * W2[j,n]
// grid (NN/1024, FJG); plain stores, no atomics.
// ---------------------------------------------------------------------------
__global__ __launch_bounds__(256) void k_final(const float* __restrict__ W2,
                                               const float* __restrict__ t,
                                               const unsigned* __restrict__ cnt,
                                               float* __restrict__ part2) {
    __shared__ float tld[GG * 128];
    const int tj = threadIdx.x;
    const int j0 = blockIdx.y * 128;
    const int nbase = blockIdx.x * 1024;
    for (int i = threadIdx.x; i < GG * 128; i += 256) {
        const int g = i >> 7;
        const int jj = i & 127;
        unsigned c = cnt[g];
        if (c < 1u) c = 1u;
        tld[i] = t[(size_t)g * HH + j0 + jj] * (1.0f / (float)c);
    }
    __syncthreads();
    float4 acc[GG];
    #pragma unroll
    for (int g = 0; g < GG; ++g) acc[g] = make_float4(0.f, 0.f, 0.f, 0.f);
    for (int jj = 0; jj < 128; ++jj) {
        const int jv = j0 + jj;
        float4 w = reinterpret_cast<const float4*>(W2 + (size_t)jv * NN + nbase)[tj];
        #pragma unroll
        for (int g = 0; g < GG; ++g) {
            const float tv = tld[g * 128 + jj];
            acc[g].x = fmaf(tv, w.x, acc[g].x);
            acc[g].y = fmaf(tv, w.y, acc[g].y);
            acc[g].z = fmaf(tv, w.z, acc[g].z);
            acc[g].w = fmaf(tv, w.w, acc[g].w);
        }
    }
    float4* p4 = reinterpret_cast<float4*>(part2);
    #pragma unroll
    for (int g = 0; g < GG; ++g)
        p4[((size_t)(blockIdx.y * GG + g) * NN + nbase) / 4 + tj] = acc[g];
}

// Final stage B: out[g][n] = b2[n] + sum_jg part2[jg][g][n]
__global__ __launch_bounds__(256) void k_fin2(const float* __restrict__ part2,
                                              const float* __restrict__ b2,
                                              float* __restrict__ out) {
    const int idx = blockIdx.x * 256 + threadIdx.x;    // float4 index into out
    const int g = idx / (NN / 4);
    const int n4 = idx % (NN / 4);
    const float4* p4 = reinterpret_cast<const float4*>(part2);
    float4 acc = reinterpret_cast<const float4*>(b2)[n4];
    for (int jg = 0; jg < FJG; ++jg) {
        const float4 v = p4[((size_t)(jg * GG + g) * NN) / 4 + n4];
        acc.x += v.x; acc.y += v.y; acc.z += v.z; acc.w += v.w;
    }
    reinterpret_cast<float4*>(out)[idx] = acc;
}

extern "C" void kernel_launch(void* const* d_in, const int* in_sizes, int n_in,
                              void* d_out, int out_size, void* d_ws, size_t ws_size,
                              hipStream_t stream) {
    const float* x  = (const float*)d_in[0];
    const float* W1 = (const float*)d_in[1];
    const float* b1 = (const float*)d_in[2];
    const float* W2 = (const float*)d_in[3];
    const float* b2 = (const float*)d_in[4];
    const int* batch = (const int*)d_in[5];
    float* out = (float*)d_out;

    char* ws = (char*)d_ws;
    size_t off = 0;
    auto alloc = [&](size_t bytes) -> char* {
        char* p = ws + off;
        off = (off + bytes + 255) & ~(size_t)255;
        return p;
    };
    uint4*    Mh      = (uint4*)   alloc((size_t)NN * HH * 2);   // bf16 M (dinv-scaled)
    uint4*    W1h     = (uint4*)   alloc((size_t)NN * HH * 2);   // bf16 W1; REUSED as hB
    uint4*    hB      = W1h;   // h overlays W1h (dead after k_spmm1; stream-serial)
    char*     zbegin  = ws + off;
    float*    t       = (float*)   alloc((size_t)GG * HH * 4);
    unsigned* colfill = (unsigned*)alloc((size_t)NN * 4);
    unsigned* cnt     = (unsigned*)alloc((size_t)GG * 4);
    char*     zend    = ws + off;
    float*    s       = (float*)   alloc((size_t)GG * NN * 4);
    float*    dinv    = (float*)   alloc((size_t)NN * 4);
    unsigned* degX    = (unsigned*)alloc((size_t)NN * 4);
    unsigned* degA    = (unsigned*)alloc((size_t)NN * 4);
    unsigned* csrX    = (unsigned*)alloc((size_t)NN * STR * 4);  // 4 MB
    unsigned* csrA    = (unsigned*)alloc((size_t)NN * STR * 4);  // 4 MB (contiguous)
    unsigned* cscA    = (unsigned*)alloc((size_t)NN * STR * 4);
    // part (poolA->poolB, 8 MB) and part2 (final->fin2, 8 MB) overlay the
    // csrX+csrA region: csrX/csrA are dead by the time poolA runs, and part
    // is dead before k_final writes part2 (stream-serial).
    float*    part    = (float*)csrX;
    float*    part2   = (float*)csrX;
    (void)ws_size; (void)in_sizes; (void)n_in; (void)out_size;

    hipMemsetAsync(zbegin, 0, (size_t)(zend - zbegin), stream);

    k_cvt<<<(NN * HH / 8) / 256, 256, 0, stream>>>(W1, (uint4*)W1h);
    k_build<<<NN, 256, 0, stream>>>(x, colfill, degX, degA, csrX, csrA, cscA);
    k_prep<<<NN / 256, 256, 0, stream>>>(colfill, batch, dinv, cnt);
    k_s<<<NN / 256, 256, 0, stream>>>(degA, csrA, dinv, batch, s);
    k_spmm1<<<dim3(NN / 2, NCH), 128, 0, stream>>>(W1h, degX, csrX, dinv, Mh);
    k_conv1<<<dim3(NN / 2, NCH), 128, 0, stream>>>(Mh, b1, dinv, colfill, cscA, hB);
    k_poolA<<<dim3(HH / 2048, PRG), 256, 0, stream>>>(hB, s, part);
    k_poolB<<<(GG * HH / 4) / 256, 256, 0, stream>>>(part, t);
    k_final<<<dim3(NN / 1024, FJG), 256, 0, stream>>>(W2, t, cnt, part2);
    k_fin2<<<(GG * NN / 4) / 256, 256, 0, stream>>>(part2, b2, out);
}

// Round 7
// 632.782 us; speedup vs baseline: 1.8215x; 1.0104x over previous
//
#include <hip/hip_runtime.h>
#include <hip/hip_bf16.h>

#define NN 8192
#define HH 4096
#define GG 8
#define STR 128            // fixed stride for per-node edge lists (max deg ~57)
#define NCH 32             // H chunks
#define CHU 16             // uint4 per chunk (= 128 cols = 256 B/row -> 2 MB/chunk)
#define PRG 64             // pool row-groups (partial-reduction factor)
#define FJG 32             // final j-groups

// ---------------------------------------------------------------------------
// bf16 helpers (packed 2x bf16 per u32; element 2q in low 16 bits)
// ---------------------------------------------------------------------------
__device__ inline unsigned bf16rne(float f) {
    unsigned u = __float_as_uint(f);
    unsigned r = 0x7fffu + ((u >> 16) & 1u);
    return (u + r) >> 16;
}
__device__ inline unsigned pack2(float lo, float hi) {
    return bf16rne(lo) | (bf16rne(hi) << 16);
}
__device__ inline void acc8(float* __restrict__ acc, uint4 v) {
    const unsigned* pu = reinterpret_cast<const unsigned*>(&v);
    #pragma unroll
    for (int q = 0; q < 4; ++q) {
        const unsigned u = pu[q];
        acc[2 * q]     += __uint_as_float(u << 16);
        acc[2 * q + 1] += __uint_as_float(u & 0xffff0000u);
    }
}
__device__ inline void unpack8(uint4 v, float* __restrict__ h) {
    const unsigned* pu = reinterpret_cast<const unsigned*>(&v);
    #pragma unroll
    for (int q = 0; q < 4; ++q) {
        const unsigned u = pu[q];
        h[2 * q]     = __uint_as_float(u << 16);
        h[2 * q + 1] = __uint_as_float(u & 0xffff0000u);
    }
}

// fp32 -> packed bf16; 8 elems per thread
__global__ __launch_bounds__(256) void k_cvt(const float* __restrict__ src,
                                             uint4* __restrict__ dst) {
    const size_t i = (size_t)blockIdx.x * 256 + threadIdx.x;
    const float4 a = reinterpret_cast<const float4*>(src)[2 * i];
    const float4 b = reinterpret_cast<const float4*>(src)[2 * i + 1];
    uint4 o;
    o.x = pack2(a.x, a.y);
    o.y = pack2(a.z, a.w);
    o.z = pack2(b.x, b.y);
    o.w = pack2(b.z, b.w);
    dst[i] = o;
}

// ---------------------------------------------------------------------------
// Single-pass graph build (reads x ONCE).
// csrX / cscA store PRE-SHIFTED byte offsets (idx << 13 = idx * HH * 2B) for
// the gather kernels; csrA stores plain indices (consumed by k_s).
// ---------------------------------------------------------------------------
__global__ __launch_bounds__(256) void k_build(const float* __restrict__ x,
                                               unsigned* __restrict__ colfill,
                                               unsigned* __restrict__ degX,
                                               unsigned* __restrict__ degA,
                                               unsigned* __restrict__ csrX,
                                               unsigned* __restrict__ csrA,
                                               unsigned* __restrict__ cscA) {
    const int r = blockIdx.x;
    __shared__ unsigned px, pa;
    if (threadIdx.x == 0) { px = 0u; pa = 0u; }
    __syncthreads();
    const float4* xr = reinterpret_cast<const float4*>(x + (size_t)r * NN);
    #pragma unroll
    for (int i = 0; i < NN / (4 * 256); ++i) {
        const int c4 = i * 256 + threadIdx.x;
        float4 v = xr[c4];
        const float* vp = reinterpret_cast<const float*>(&v);
        #pragma unroll
        for (int k = 0; k < 4; ++k) {
            const int c = c4 * 4 + k;
            const bool nzx = (vp[k] != 0.0f);
            const bool nzA = nzx || (c == r);
            if (nzx) {
                unsigned p = atomicAdd(&px, 1u);
                if (p < STR) csrX[(size_t)r * STR + p] = (unsigned)c << 13;
            }
            if (nzA) {
                unsigned p = atomicAdd(&pa, 1u);
                if (p < STR) csrA[(size_t)r * STR + p] = (unsigned)c;
                unsigned q = atomicAdd(&colfill[c], 1u);
                if (q < STR) cscA[(size_t)c * STR + q] = (unsigned)r << 13;
            }
        }
    }
    __syncthreads();
    if (threadIdx.x == 0) { degX[r] = px; degA[r] = pa; }
}

// dinv = rsqrt(deg); batch counts
__global__ __launch_bounds__(256) void k_prep(const unsigned* __restrict__ colfill,
                                              const int* __restrict__ batch,
                                              float* __restrict__ dinv,
                                              unsigned* __restrict__ cnt) {
    const int i = blockIdx.x * 256 + threadIdx.x;
    dinv[i] = rsqrtf((float)colfill[i]);
    atomicAdd(&cnt[batch[i]], 1u);
}

// pooled adjacency: s[g][r] = dinv[r] * sum_{c in rowA(r), batch[c]==g} dinv[c]
__global__ __launch_bounds__(256) void k_s(const unsigned* __restrict__ degA,
                                           const unsigned* __restrict__ csrA,
                                           const float* __restrict__ dinv,
                                           const int* __restrict__ batch,
                                           float* __restrict__ s) {
    const int r = blockIdx.x * 256 + threadIdx.x;
    unsigned deg = degA[r];
    if (deg > STR) deg = STR;
    float bins[GG];
    #pragma unroll
    for (int g = 0; g < GG; ++g) bins[g] = 0.0f;
    for (unsigned e = 0; e < deg; ++e) {
        const unsigned c = csrA[(size_t)r * STR + e];
        const float d = dinv[c];
        const int gb = batch[c];
        #pragma unroll
        for (int g = 0; g < GG; ++g) bins[g] += (gb == g) ? d : 0.0f;
    }
    const float dr = dinv[r];
    #pragma unroll
    for (int g = 0; g < GG; ++g) s[(size_t)g * NN + r] = dr * bins[g];
}

// ---------------------------------------------------------------------------
// Chunked SpMM1: per (node-pair, chunk) block. Wave w handles node 2*bx+w.
// Within a wave: 4 edge slots x 16 lanes x 8 bf16 = 128-col chunk.
// Edge lists hold byte offsets; loads are uniform-base + 32-bit voffset.
// Mh[r, ch] = bf16( dinv[r] * sum_{c in csrX(r)} W1h[c, ch] )
// ---------------------------------------------------------------------------
__global__ __launch_bounds__(128) void k_spmm1(const char* __restrict__ W1b,
                                               const unsigned* __restrict__ degX,
                                               const unsigned* __restrict__ csrX,
                                               const float* __restrict__ dinv,
                                               uint4* __restrict__ Mh) {
    const int wid  = threadIdx.x >> 6;
    const int lane = threadIdx.x & 63;
    const int node = blockIdx.x * 2 + wid;
    const int ch   = blockIdx.y;
    const int sub  = lane >> 4;
    const int l16  = lane & 15;
    __shared__ unsigned offs[2][STR];
    unsigned deg = degX[node];
    if (deg > STR) deg = STR;
    for (unsigned i = lane; i < deg; i += 64)
        offs[wid][i] = csrX[(size_t)node * STR + i];
    __syncthreads();

    const unsigned loff = (unsigned)(ch * CHU + l16) * 16u;
    float acc[8];
    #pragma unroll
    for (int q = 0; q < 8; ++q) acc[q] = 0.0f;
    unsigned e = sub;
    for (; e + 4 < deg; e += 8) {
        const uint4 va = *reinterpret_cast<const uint4*>(W1b + (offs[wid][e] + loff));
        const uint4 vb = *reinterpret_cast<const uint4*>(W1b + (offs[wid][e + 4] + loff));
        acc8(acc, va);
        acc8(acc, vb);
    }
    if (e < deg)
        acc8(acc, *reinterpret_cast<const uint4*>(W1b + (offs[wid][e] + loff)));

    #pragma unroll
    for (int q = 0; q < 8; ++q) {
        acc[q] += __shfl_xor(acc[q], 16);
        acc[q] += __shfl_xor(acc[q], 32);
    }
    if (sub == 0) {
        const float dr = dinv[node];
        uint4 o;
        o.x = pack2(dr * acc[0], dr * acc[1]);
        o.y = pack2(dr * acc[2], dr * acc[3]);
        o.z = pack2(dr * acc[4], dr * acc[5]);
        o.w = pack2(dr * acc[6], dr * acc[7]);
        Mh[(size_t)node * (HH / 8) + ch * CHU + l16] = o;
    }
}

// ---------------------------------------------------------------------------
// Chunked conv1: hB[c, ch] = bf16( relu(dinv[c]*sum_{rn in cscA(c)} Mh[rn,ch] + b1) )
// (Mh pre-scaled by dinv[rn].)
// ---------------------------------------------------------------------------
__global__ __launch_bounds__(128) void k_conv1(const char* __restrict__ Mb,
                                               const float* __restrict__ b1,
                                               const float* __restrict__ dinv,
                                               const unsigned* __restrict__ colfill,
                                               const unsigned* __restrict__ cscA,
                                               uint4* __restrict__ hB) {
    const int wid  = threadIdx.x >> 6;
    const int lane = threadIdx.x & 63;
    const int node = blockIdx.x * 2 + wid;
    const int ch   = blockIdx.y;
    const int sub  = lane >> 4;
    const int l16  = lane & 15;
    __shared__ unsigned offs[2][STR];
    unsigned deg = colfill[node];
    if (deg > STR) deg = STR;
    for (unsigned i = lane; i < deg; i += 64)
        offs[wid][i] = cscA[(size_t)node * STR + i];
    __syncthreads();

    const unsigned loff = (unsigned)(ch * CHU + l16) * 16u;
    float acc[8];
    #pragma unroll
    for (int q = 0; q < 8; ++q) acc[q] = 0.0f;
    unsigned e = sub;
    for (; e + 4 < deg; e += 8) {
        const uint4 va = *reinterpret_cast<const uint4*>(Mb + (offs[wid][e] + loff));
        const uint4 vb = *reinterpret_cast<const uint4*>(Mb + (offs[wid][e + 4] + loff));
        acc8(acc, va);
        acc8(acc, vb);
    }
    if (e < deg)
        acc8(acc, *reinterpret_cast<const uint4*>(Mb + (offs[wid][e] + loff)));

    #pragma unroll
    for (int q = 0; q < 8; ++q) {
        acc[q] += __shfl_xor(acc[q], 16);
        acc[q] += __shfl_xor(acc[q], 32);
    }
    if (sub == 0) {
        const float dc = dinv[node];
        const float4 ba = reinterpret_cast<const float4*>(b1)[ch * (CHU * 2) + l16 * 2];
        const float4 bb = reinterpret_cast<const float4*>(b1)[ch * (CHU * 2) + l16 * 2 + 1];
        float h[8];
        h[0] = fmaxf(fmaf(dc, acc[0], ba.x), 0.0f);
        h[1] = fmaxf(fmaf(dc, acc[1], ba.y), 0.0f);
        h[2] = fmaxf(fmaf(dc, acc[2], ba.z), 0.0f);
        h[3] = fmaxf(fmaf(dc, acc[3], ba.w), 0.0f);
        h[4] = fmaxf(fmaf(dc, acc[4], bb.x), 0.0f);
        h[5] = fmaxf(fmaf(dc, acc[5], bb.y), 0.0f);
        h[6] = fmaxf(fmaf(dc, acc[6], bb.z), 0.0f);
        h[7] = fmaxf(fmaf(dc, acc[7], bb.w), 0.0f);
        uint4 o;
        o.x = pack2(h[0], h[1]);
        o.y = pack2(h[2], h[3]);
        o.z = pack2(h[4], h[5]);
        o.w = pack2(h[6], h[7]);
        hB[(size_t)node * (HH / 8) + ch * CHU + l16] = o;
    }
}

// ---------------------------------------------------------------------------
// Pool stage A: partial t per row-group, NO atomics.
// ---------------------------------------------------------------------------
__global__ __launch_bounds__(256) void k_poolA(const uint4* __restrict__ hB,
                                               const float* __restrict__ s,
                                               float* __restrict__ part) {
    const int j = blockIdx.x * 256 + threadIdx.x;      // uint4 col index
    const int c0 = blockIdx.y * (NN / PRG);            // 128 rows
    __shared__ float s_t[GG * (NN / PRG)];
    for (int i = threadIdx.x; i < GG * (NN / PRG); i += 256) {
        const int g = i / (NN / PRG);
        const int cc = i % (NN / PRG);
        s_t[i] = s[(size_t)g * NN + c0 + cc];
    }
    __syncthreads();
    float tacc[GG][8];
    #pragma unroll
    for (int g = 0; g < GG; ++g)
        #pragma unroll
        for (int q = 0; q < 8; ++q) tacc[g][q] = 0.0f;
    for (int cc = 0; cc < NN / PRG; ++cc) {
        const uint4 v = hB[(size_t)(c0 + cc) * (HH / 8) + j];
        float hv[8];
        unpack8(v, hv);
        #pragma unroll
        for (int g = 0; g < GG; ++g) {
            const float sv = s_t[g * (NN / PRG) + cc];
            #pragma unroll
            for (int q = 0; q < 8; ++q) tacc[g][q] = fmaf(sv, hv[q], tacc[g][q]);
        }
    }
    float4* p4 = reinterpret_cast<float4*>(part);
    #pragma unroll
    for (int g = 0; g < GG; ++g) {
        const size_t base = ((size_t)(blockIdx.y * GG + g) * HH) / 4 + j * 2;
        p4[base]     = make_float4(tacc[g][0], tacc[g][1], tacc[g][2], tacc[g][3]);
        p4[base + 1] = make_float4(tacc[g][4], tacc[g][5], tacc[g][6], tacc[g][7]);
    }
}

// Pool stage B: t[g][j] = sum_rg part[rg][g][j]
__global__ __launch_bounds__(256) void k_poolB(const float* __restrict__ part,
                                               float* __restrict__ t) {
    const int idx = blockIdx.x * 256 + threadIdx.x;    // float4 index into t
    const int g = idx / (HH / 4);
    const int j4 = idx % (HH / 4);
    const float4* p4 = reinterpret_cast<const float4*>(part);
    float4 acc = make_float4(0.f, 0.f, 0.f, 0.f);
    for (int rg = 0; rg < PRG; ++rg) {
        const float4 v = p4[((size_t)(rg * GG + g) * HH) / 4 + j4];
        acc.x += v.x; acc.y += v.y; acc.z += v.z; acc.w += v.w;
    }
    reinterpret_cast<float4*>(t)[idx] = acc;
}

// ---------------------------------------------------------------------------
// Final stage A: part2[jg][g][n] = sum_{j in jgroup} (t[g,j]/cnt[g]) * W2[j,n]
// ---------------------------------------------------------------------------
__global__ __launch_bounds__(256) void k_final(const float* __restrict__ W2,
                                               const float* __restrict__ t,
                                               const unsigned* __restrict__ cnt,
                                               float* __restrict__ part2) {
    __shared__ float tld[GG * 128];
    const int tj = threadIdx.x;
    const int j0 = blockIdx.y * 128;
    const int nbase = blockIdx.x * 1024;
    for (int i = threadIdx.x; i < GG * 128; i += 256) {
        const int g = i >> 7;
        const int jj = i & 127;
        unsigned c = cnt[g];
        if (c < 1u) c = 1u;
        tld[i] = t[(size_t)g * HH + j0 + jj] * (1.0f / (float)c);
    }
    __syncthreads();
    float4 acc[GG];
    #pragma unroll
    for (int g = 0; g < GG; ++g) acc[g] = make_float4(0.f, 0.f, 0.f, 0.f);
    for (int jj = 0; jj < 128; ++jj) {
        const int jv = j0 + jj;
        float4 w = reinterpret_cast<const float4*>(W2 + (size_t)jv * NN + nbase)[tj];
        #pragma unroll
        for (int g = 0; g < GG; ++g) {
            const float tv = tld[g * 128 + jj];
            acc[g].x = fmaf(tv, w.x, acc[g].x);
            acc[g].y = fmaf(tv, w.y, acc[g].y);
            acc[g].z = fmaf(tv, w.z, acc[g].z);
            acc[g].w = fmaf(tv, w.w, acc[g].w);
        }
    }
    float4* p4 = reinterpret_cast<float4*>(part2);
    #pragma unroll
    for (int g = 0; g < GG; ++g)
        p4[((size_t)(blockIdx.y * GG + g) * NN + nbase) / 4 + tj] = acc[g];
}

// Final stage B: out[g][n] = b2[n] + sum_jg part2[jg][g][n]
__global__ __launch_bounds__(256) void k_fin2(const float* __restrict__ part2,
                                              const float* __restrict__ b2,
                                              float* __restrict__ out) {
    const int idx = blockIdx.x * 256 + threadIdx.x;    // float4 index into out
    const int g = idx / (NN / 4);
    const int n4 = idx % (NN / 4);
    const float4* p4 = reinterpret_cast<const float4*>(part2);
    float4 acc = reinterpret_cast<const float4*>(b2)[n4];
    for (int jg = 0; jg < FJG; ++jg) {
        const float4 v = p4[((size_t)(jg * GG + g) * NN) / 4 + n4];
        acc.x += v.x; acc.y += v.y; acc.z += v.z; acc.w += v.w;
    }
    reinterpret_cast<float4*>(out)[idx] = acc;
}

extern "C" void kernel_launch(void* const* d_in, const int* in_sizes, int n_in,
                              void* d_out, int out_size, void* d_ws, size_t ws_size,
                              hipStream_t stream) {
    const float* x  = (const float*)d_in[0];
    const float* W1 = (const float*)d_in[1];
    const float* b1 = (const float*)d_in[2];
    const float* W2 = (const float*)d_in[3];
    const float* b2 = (const float*)d_in[4];
    const int* batch = (const int*)d_in[5];
    float* out = (float*)d_out;

    char* ws = (char*)d_ws;
    size_t off = 0;
    auto alloc = [&](size_t bytes) -> char* {
        char* p = ws + off;
        off = (off + bytes + 255) & ~(size_t)255;
        return p;
    };
    uint4*    Mh      = (uint4*)   alloc((size_t)NN * HH * 2);   // bf16 M (dinv-scaled)
    uint4*    W1h     = (uint4*)   alloc((size_t)NN * HH * 2);   // bf16 W1; REUSED as hB
    uint4*    hB      = W1h;   // h overlays W1h (dead after k_spmm1; stream-serial)
    char*     zbegin  = ws + off;
    float*    t       = (float*)   alloc((size_t)GG * HH * 4);
    unsigned* colfill = (unsigned*)alloc((size_t)NN * 4);
    unsigned* cnt     = (unsigned*)alloc((size_t)GG * 4);
    char*     zend    = ws + off;
    float*    s       = (float*)   alloc((size_t)GG * NN * 4);
    float*    dinv    = (float*)   alloc((size_t)NN * 4);
    unsigned* degX    = (unsigned*)alloc((size_t)NN * 4);
    unsigned* degA    = (unsigned*)alloc((size_t)NN * 4);
    unsigned* csrX    = (unsigned*)alloc((size_t)NN * STR * 4);  // 4 MB
    unsigned* csrA    = (unsigned*)alloc((size_t)NN * STR * 4);  // 4 MB (contiguous)
    unsigned* cscA    = (unsigned*)alloc((size_t)NN * STR * 4);
    // part (poolA->poolB, 8 MB) and part2 (final->fin2, 8 MB) overlay the
    // csrX+csrA region (dead by then; stream-serial).
    float*    part    = (float*)csrX;
    float*    part2   = (float*)csrX;
    (void)ws_size; (void)in_sizes; (void)n_in; (void)out_size;

    hipMemsetAsync(zbegin, 0, (size_t)(zend - zbegin), stream);

    k_cvt<<<(NN * HH / 8) / 256, 256, 0, stream>>>(W1, (uint4*)W1h);
    k_build<<<NN, 256, 0, stream>>>(x, colfill, degX, degA, csrX, csrA, cscA);
    k_prep<<<NN / 256, 256, 0, stream>>>(colfill, batch, dinv, cnt);
    k_s<<<NN / 256, 256, 0, stream>>>(degA, csrA, dinv, batch, s);
    k_spmm1<<<dim3(NN / 2, NCH), 128, 0, stream>>>((const char*)W1h, degX, csrX, dinv, Mh);
    k_conv1<<<dim3(NN / 2, NCH), 128, 0, stream>>>((const char*)Mh, b1, dinv, colfill, cscA, hB);
    k_poolA<<<dim3(HH / 2048, PRG), 256, 0, stream>>>(hB, s, part);
    k_poolB<<<(GG * HH / 4) / 256, 256, 0, stream>>>(part, t);
    k_final<<<dim3(NN / 1024, FJG), 256, 0, stream>>>(W2, t, cnt, part2);
    k_fin2<<<(GG * NN / 4) / 256, 256, 0, stream>>>(part2, b2, out);
}

// Round 8
// 627.877 us; speedup vs baseline: 1.8358x; 1.0078x over previous
//
#include <hip/hip_runtime.h>
#include <hip/hip_bf16.h>

#define NN 8192
#define HH 4096
#define GG 8
#define STR 128            // fixed stride for per-node edge lists (max deg ~57)
#define NCH 32             // H chunks
#define CHU 16             // uint4 per chunk (= 128 cols = 256 B/row -> 2 MB/chunk)
#define PRG 64             // pool row-groups (partial-reduction factor)
#define FJG 32             // final j-groups

// ---------------------------------------------------------------------------
// bf16 helpers (packed 2x bf16 per u32; element 2q in low 16 bits)
// ---------------------------------------------------------------------------
__device__ inline unsigned bf16rne(float f) {
    unsigned u = __float_as_uint(f);
    unsigned r = 0x7fffu + ((u >> 16) & 1u);
    return (u + r) >> 16;
}
__device__ inline unsigned pack2(float lo, float hi) {
    return bf16rne(lo) | (bf16rne(hi) << 16);
}
// packed accumulate: acc2[q] += (lo, hi) via v_pk_add_f32 (1 instr / 2 elems)
__device__ inline void acc8p(float2* __restrict__ acc2, uint4 v) {
    const unsigned* pu = reinterpret_cast<const unsigned*>(&v);
    #pragma unroll
    for (int q = 0; q < 4; ++q) {
        const unsigned u = pu[q];
        float2 t;
        t.x = __uint_as_float(u << 16);
        t.y = __uint_as_float(u & 0xffff0000u);
        asm("v_pk_add_f32 %0, %1, %0" : "+v"(acc2[q]) : "v"(t));
    }
}
__device__ inline void unpack8(uint4 v, float* __restrict__ h) {
    const unsigned* pu = reinterpret_cast<const unsigned*>(&v);
    #pragma unroll
    for (int q = 0; q < 4; ++q) {
        const unsigned u = pu[q];
        h[2 * q]     = __uint_as_float(u << 16);
        h[2 * q + 1] = __uint_as_float(u & 0xffff0000u);
    }
}

// fp32 -> packed bf16; 8 elems per thread
__global__ __launch_bounds__(256) void k_cvt(const float* __restrict__ src,
                                             uint4* __restrict__ dst) {
    const size_t i = (size_t)blockIdx.x * 256 + threadIdx.x;
    const float4 a = reinterpret_cast<const float4*>(src)[2 * i];
    const float4 b = reinterpret_cast<const float4*>(src)[2 * i + 1];
    uint4 o;
    o.x = pack2(a.x, a.y);
    o.y = pack2(a.z, a.w);
    o.z = pack2(b.x, b.y);
    o.w = pack2(b.z, b.w);
    dst[i] = o;
}

// ---------------------------------------------------------------------------
// Single-pass graph build (reads x ONCE).
// csrX / cscA store PRE-SHIFTED byte offsets (idx << 13 = idx * HH * 2B) for
// the gather kernels; csrA stores plain indices (consumed by k_s).
// ---------------------------------------------------------------------------
__global__ __launch_bounds__(256) void k_build(const float* __restrict__ x,
                                               unsigned* __restrict__ colfill,
                                               unsigned* __restrict__ degX,
                                               unsigned* __restrict__ degA,
                                               unsigned* __restrict__ csrX,
                                               unsigned* __restrict__ csrA,
                                               unsigned* __restrict__ cscA) {
    const int r = blockIdx.x;
    __shared__ unsigned px, pa;
    if (threadIdx.x == 0) { px = 0u; pa = 0u; }
    __syncthreads();
    const float4* xr = reinterpret_cast<const float4*>(x + (size_t)r * NN);
    #pragma unroll
    for (int i = 0; i < NN / (4 * 256); ++i) {
        const int c4 = i * 256 + threadIdx.x;
        float4 v = xr[c4];
        const float* vp = reinterpret_cast<const float*>(&v);
        #pragma unroll
        for (int k = 0; k < 4; ++k) {
            const int c = c4 * 4 + k;
            const bool nzx = (vp[k] != 0.0f);
            const bool nzA = nzx || (c == r);
            if (nzx) {
                unsigned p = atomicAdd(&px, 1u);
                if (p < STR) csrX[(size_t)r * STR + p] = (unsigned)c << 13;
            }
            if (nzA) {
                unsigned p = atomicAdd(&pa, 1u);
                if (p < STR) csrA[(size_t)r * STR + p] = (unsigned)c;
                unsigned q = atomicAdd(&colfill[c], 1u);
                if (q < STR) cscA[(size_t)c * STR + q] = (unsigned)r << 13;
            }
        }
    }
    __syncthreads();
    if (threadIdx.x == 0) { degX[r] = px; degA[r] = pa; }
}

// dinv = rsqrt(deg); batch counts
__global__ __launch_bounds__(256) void k_prep(const unsigned* __restrict__ colfill,
                                              const int* __restrict__ batch,
                                              float* __restrict__ dinv,
                                              unsigned* __restrict__ cnt) {
    const int i = blockIdx.x * 256 + threadIdx.x;
    dinv[i] = rsqrtf((float)colfill[i]);
    atomicAdd(&cnt[batch[i]], 1u);
}

// pooled adjacency: s[g][r] = dinv[r] * sum_{c in rowA(r), batch[c]==g} dinv[c]
__global__ __launch_bounds__(256) void k_s(const unsigned* __restrict__ degA,
                                           const unsigned* __restrict__ csrA,
                                           const float* __restrict__ dinv,
                                           const int* __restrict__ batch,
                                           float* __restrict__ s) {
    const int r = blockIdx.x * 256 + threadIdx.x;
    unsigned deg = degA[r];
    if (deg > STR) deg = STR;
    float bins[GG];
    #pragma unroll
    for (int g = 0; g < GG; ++g) bins[g] = 0.0f;
    for (unsigned e = 0; e < deg; ++e) {
        const unsigned c = csrA[(size_t)r * STR + e];
        const float d = dinv[c];
        const int gb = batch[c];
        #pragma unroll
        for (int g = 0; g < GG; ++g) bins[g] += (gb == g) ? d : 0.0f;
    }
    const float dr = dinv[r];
    #pragma unroll
    for (int g = 0; g < GG; ++g) s[(size_t)g * NN + r] = dr * bins[g];
}

// ---------------------------------------------------------------------------
// Chunked SpMM1: per (node-pair, chunk) block. Wave w handles node 2*bx+w.
// Within a wave: 4 edge slots x 16 lanes x 8 bf16 = 128-col chunk.
// 4-deep staged loads; packed v_pk_add_f32 accumulation.
// Mh[r, ch] = bf16( dinv[r] * sum_{c in csrX(r)} W1h[c, ch] )
// ---------------------------------------------------------------------------
__global__ __launch_bounds__(128) void k_spmm1(const char* __restrict__ W1b,
                                               const unsigned* __restrict__ degX,
                                               const unsigned* __restrict__ csrX,
                                               const float* __restrict__ dinv,
                                               uint4* __restrict__ Mh) {
    const int wid  = threadIdx.x >> 6;
    const int lane = threadIdx.x & 63;
    const int node = blockIdx.x * 2 + wid;
    const int ch   = blockIdx.y;
    const int sub  = lane >> 4;
    const int l16  = lane & 15;
    __shared__ unsigned offs[2][STR];
    unsigned deg = degX[node];
    if (deg > STR) deg = STR;
    for (unsigned i = lane; i < deg; i += 64)
        offs[wid][i] = csrX[(size_t)node * STR + i];
    __syncthreads();

    const unsigned loff = (unsigned)(ch * CHU + l16) * 16u;
    float2 acc2[4];
    #pragma unroll
    for (int q = 0; q < 4; ++q) acc2[q] = make_float2(0.f, 0.f);
    unsigned e = sub;
    for (; e + 12 < deg; e += 16) {
        const uint4 v0 = *reinterpret_cast<const uint4*>(W1b + (offs[wid][e]      + loff));
        const uint4 v1 = *reinterpret_cast<const uint4*>(W1b + (offs[wid][e + 4]  + loff));
        const uint4 v2 = *reinterpret_cast<const uint4*>(W1b + (offs[wid][e + 8]  + loff));
        const uint4 v3 = *reinterpret_cast<const uint4*>(W1b + (offs[wid][e + 12] + loff));
        acc8p(acc2, v0); acc8p(acc2, v1); acc8p(acc2, v2); acc8p(acc2, v3);
    }
    for (; e < deg; e += 4)
        acc8p(acc2, *reinterpret_cast<const uint4*>(W1b + (offs[wid][e] + loff)));

    #pragma unroll
    for (int q = 0; q < 4; ++q) {
        acc2[q].x += __shfl_xor(acc2[q].x, 16);
        acc2[q].y += __shfl_xor(acc2[q].y, 16);
        acc2[q].x += __shfl_xor(acc2[q].x, 32);
        acc2[q].y += __shfl_xor(acc2[q].y, 32);
    }
    if (sub == 0) {
        const float dr = dinv[node];
        uint4 o;
        o.x = pack2(dr * acc2[0].x, dr * acc2[0].y);
        o.y = pack2(dr * acc2[1].x, dr * acc2[1].y);
        o.z = pack2(dr * acc2[2].x, dr * acc2[2].y);
        o.w = pack2(dr * acc2[3].x, dr * acc2[3].y);
        Mh[(size_t)node * (HH / 8) + ch * CHU + l16] = o;
    }
}

// ---------------------------------------------------------------------------
// Chunked conv1: hB[c, ch] = bf16( relu(dinv[c]*sum_{rn in cscA(c)} Mh[rn,ch] + b1) )
// (Mh pre-scaled by dinv[rn].)
// ---------------------------------------------------------------------------
__global__ __launch_bounds__(128) void k_conv1(const char* __restrict__ Mb,
                                               const float* __restrict__ b1,
                                               const float* __restrict__ dinv,
                                               const unsigned* __restrict__ colfill,
                                               const unsigned* __restrict__ cscA,
                                               uint4* __restrict__ hB) {
    const int wid  = threadIdx.x >> 6;
    const int lane = threadIdx.x & 63;
    const int node = blockIdx.x * 2 + wid;
    const int ch   = blockIdx.y;
    const int sub  = lane >> 4;
    const int l16  = lane & 15;
    __shared__ unsigned offs[2][STR];
    unsigned deg = colfill[node];
    if (deg > STR) deg = STR;
    for (unsigned i = lane; i < deg; i += 64)
        offs[wid][i] = cscA[(size_t)node * STR + i];
    __syncthreads();

    const unsigned loff = (unsigned)(ch * CHU + l16) * 16u;
    float2 acc2[4];
    #pragma unroll
    for (int q = 0; q < 4; ++q) acc2[q] = make_float2(0.f, 0.f);
    unsigned e = sub;
    for (; e + 12 < deg; e += 16) {
        const uint4 v0 = *reinterpret_cast<const uint4*>(Mb + (offs[wid][e]      + loff));
        const uint4 v1 = *reinterpret_cast<const uint4*>(Mb + (offs[wid][e + 4]  + loff));
        const uint4 v2 = *reinterpret_cast<const uint4*>(Mb + (offs[wid][e + 8]  + loff));
        const uint4 v3 = *reinterpret_cast<const uint4*>(Mb + (offs[wid][e + 12] + loff));
        acc8p(acc2, v0); acc8p(acc2, v1); acc8p(acc2, v2); acc8p(acc2, v3);
    }
    for (; e < deg; e += 4)
        acc8p(acc2, *reinterpret_cast<const uint4*>(Mb + (offs[wid][e] + loff)));

    #pragma unroll
    for (int q = 0; q < 4; ++q) {
        acc2[q].x += __shfl_xor(acc2[q].x, 16);
        acc2[q].y += __shfl_xor(acc2[q].y, 16);
        acc2[q].x += __shfl_xor(acc2[q].x, 32);
        acc2[q].y += __shfl_xor(acc2[q].y, 32);
    }
    if (sub == 0) {
        const float dc = dinv[node];
        const float4 ba = reinterpret_cast<const float4*>(b1)[ch * (CHU * 2) + l16 * 2];
        const float4 bb = reinterpret_cast<const float4*>(b1)[ch * (CHU * 2) + l16 * 2 + 1];
        float h[8];
        h[0] = fmaxf(fmaf(dc, acc2[0].x, ba.x), 0.0f);
        h[1] = fmaxf(fmaf(dc, acc2[0].y, ba.y), 0.0f);
        h[2] = fmaxf(fmaf(dc, acc2[1].x, ba.z), 0.0f);
        h[3] = fmaxf(fmaf(dc, acc2[1].y, ba.w), 0.0f);
        h[4] = fmaxf(fmaf(dc, acc2[2].x, bb.x), 0.0f);
        h[5] = fmaxf(fmaf(dc, acc2[2].y, bb.y), 0.0f);
        h[6] = fmaxf(fmaf(dc, acc2[3].x, bb.z), 0.0f);
        h[7] = fmaxf(fmaf(dc, acc2[3].y, bb.w), 0.0f);
        uint4 o;
        o.x = pack2(h[0], h[1]);
        o.y = pack2(h[2], h[3]);
        o.z = pack2(h[4], h[5]);
        o.w = pack2(h[6], h[7]);
        hB[(size_t)node * (HH / 8) + ch * CHU + l16] = o;
    }
}

// ---------------------------------------------------------------------------
// Pool stage A: partial t per row-group, NO atomics.
// ---------------------------------------------------------------------------
__global__ __launch_bounds__(256) void k_poolA(const uint4* __restrict__ hB,
                                               const float* __restrict__ s,
                                               float* __restrict__ part) {
    const int j = blockIdx.x * 256 + threadIdx.x;      // uint4 col index
    const int c0 = blockIdx.y * (NN / PRG);            // 128 rows
    __shared__ float s_t[GG * (NN / PRG)];
    for (int i = threadIdx.x; i < GG * (NN / PRG); i += 256) {
        const int g = i / (NN / PRG);
        const int cc = i % (NN / PRG);
        s_t[i] = s[(size_t)g * NN + c0 + cc];
    }
    __syncthreads();
    float tacc[GG][8];
    #pragma unroll
    for (int g = 0; g < GG; ++g)
        #pragma unroll
        for (int q = 0; q < 8; ++q) tacc[g][q] = 0.0f;
    for (int cc = 0; cc < NN / PRG; ++cc) {
        const uint4 v = hB[(size_t)(c0 + cc) * (HH / 8) + j];
        float hv[8];
        unpack8(v, hv);
        #pragma unroll
        for (int g = 0; g < GG; ++g) {
            const float sv = s_t[g * (NN / PRG) + cc];
            #pragma unroll
            for (int q = 0; q < 8; ++q) tacc[g][q] = fmaf(sv, hv[q], tacc[g][q]);
        }
    }
    float4* p4 = reinterpret_cast<float4*>(part);
    #pragma unroll
    for (int g = 0; g < GG; ++g) {
        const size_t base = ((size_t)(blockIdx.y * GG + g) * HH) / 4 + j * 2;
        p4[base]     = make_float4(tacc[g][0], tacc[g][1], tacc[g][2], tacc[g][3]);
        p4[base + 1] = make_float4(tacc[g][4], tacc[g][5], tacc[g][6], tacc[g][7]);
    }
}

// Pool stage B: t[g][j] = sum_rg part[rg][g][j]
__global__ __launch_bounds__(256) void k_poolB(const float* __restrict__ part,
                                               float* __restrict__ t) {
    const int idx = blockIdx.x * 256 + threadIdx.x;    // float4 index into t
    const int g = idx / (HH / 4);
    const int j4 = idx % (HH / 4);
    const float4* p4 = reinterpret_cast<const float4*>(part);
    float4 acc = make_float4(0.f, 0.f, 0.f, 0.f);
    for (int rg = 0; rg < PRG; ++rg) {
        const float4 v = p4[((size_t)(rg * GG + g) * HH) / 4 + j4];
        acc.x += v.x; acc.y += v.y; acc.z += v.z; acc.w += v.w;
    }
    reinterpret_cast<float4*>(t)[idx] = acc;
}

// ---------------------------------------------------------------------------
// Final stage A: part2[jg][g][n] = sum_{j in jgroup} (t[g,j]/cnt[g]) * W2[j,n]
// ---------------------------------------------------------------------------
__global__ __launch_bounds__(256) void k_final(const float* __restrict__ W2,
                                               const float* __restrict__ t,
                                               const unsigned* __restrict__ cnt,
                                               float* __restrict__ part2) {
    __shared__ float tld[GG * 128];
    const int tj = threadIdx.x;
    const int j0 = blockIdx.y * 128;
    const int nbase = blockIdx.x * 1024;
    for (int i = threadIdx.x; i < GG * 128; i += 256) {
        const int g = i >> 7;
        const int jj = i & 127;
        unsigned c = cnt[g];
        if (c < 1u) c = 1u;
        tld[i] = t[(size_t)g * HH + j0 + jj] * (1.0f / (float)c);
    }
    __syncthreads();
    float4 acc[GG];
    #pragma unroll
    for (int g = 0; g < GG; ++g) acc[g] = make_float4(0.f, 0.f, 0.f, 0.f);
    for (int jj = 0; jj < 128; ++jj) {
        const int jv = j0 + jj;
        float4 w = reinterpret_cast<const float4*>(W2 + (size_t)jv * NN + nbase)[tj];
        #pragma unroll
        for (int g = 0; g < GG; ++g) {
            const float tv = tld[g * 128 + jj];
            acc[g].x = fmaf(tv, w.x, acc[g].x);
            acc[g].y = fmaf(tv, w.y, acc[g].y);
            acc[g].z = fmaf(tv, w.z, acc[g].z);
            acc[g].w = fmaf(tv, w.w, acc[g].w);
        }
    }
    float4* p4 = reinterpret_cast<float4*>(part2);
    #pragma unroll
    for (int g = 0; g < GG; ++g)
        p4[((size_t)(blockIdx.y * GG + g) * NN + nbase) / 4 + tj] = acc[g];
}

// Final stage B: out[g][n] = b2[n] + sum_jg part2[jg][g][n]
__global__ __launch_bounds__(256) void k_fin2(const float* __restrict__ part2,
                                              const float* __restrict__ b2,
                                              float* __restrict__ out) {
    const int idx = blockIdx.x * 256 + threadIdx.x;    // float4 index into out
    const int g = idx / (NN / 4);
    const int n4 = idx % (NN / 4);
    const float4* p4 = reinterpret_cast<const float4*>(part2);
    float4 acc = reinterpret_cast<const float4*>(b2)[n4];
    for (int jg = 0; jg < FJG; ++jg) {
        const float4 v = p4[((size_t)(jg * GG + g) * NN) / 4 + n4];
        acc.x += v.x; acc.y += v.y; acc.z += v.z; acc.w += v.w;
    }
    reinterpret_cast<float4*>(out)[idx] = acc;
}

extern "C" void kernel_launch(void* const* d_in, const int* in_sizes, int n_in,
                              void* d_out, int out_size, void* d_ws, size_t ws_size,
                              hipStream_t stream) {
    const float* x  = (const float*)d_in[0];
    const float* W1 = (const float*)d_in[1];
    const float* b1 = (const float*)d_in[2];
    const float* W2 = (const float*)d_in[3];
    const float* b2 = (const float*)d_in[4];
    const int* batch = (const int*)d_in[5];
    float* out = (float*)d_out;

    char* ws = (char*)d_ws;
    size_t off = 0;
    auto alloc = [&](size_t bytes) -> char* {
        char* p = ws + off;
        off = (off + bytes + 255) & ~(size_t)255;
        return p;
    };
    uint4*    Mh      = (uint4*)   alloc((size_t)NN * HH * 2);   // bf16 M (dinv-scaled)
    uint4*    W1h     = (uint4*)   alloc((size_t)NN * HH * 2);   // bf16 W1; REUSED as hB
    uint4*    hB      = W1h;   // h overlays W1h (dead after k_spmm1; stream-serial)
    char*     zbegin  = ws + off;
    float*    t       = (float*)   alloc((size_t)GG * HH * 4);
    unsigned* colfill = (unsigned*)alloc((size_t)NN * 4);
    unsigned* cnt     = (unsigned*)alloc((size_t)GG * 4);
    char*     zend    = ws + off;
    float*    s       = (float*)   alloc((size_t)GG * NN * 4);
    float*    dinv    = (float*)   alloc((size_t)NN * 4);
    unsigned* degX    = (unsigned*)alloc((size_t)NN * 4);
    unsigned* degA    = (unsigned*)alloc((size_t)NN * 4);
    unsigned* csrX    = (unsigned*)alloc((size_t)NN * STR * 4);  // 4 MB
    unsigned* csrA    = (unsigned*)alloc((size_t)NN * STR * 4);  // 4 MB (contiguous)
    unsigned* cscA    = (unsigned*)alloc((size_t)NN * STR * 4);
    // part (poolA->poolB, 8 MB) and part2 (final->fin2, 8 MB) overlay the
    // csrX+csrA region (dead by then; stream-serial).
    float*    part    = (float*)csrX;
    float*    part2   = (float*)csrX;
    (void)ws_size; (void)in_sizes; (void)n_in; (void)out_size;

    hipMemsetAsync(zbegin, 0, (size_t)(zend - zbegin), stream);

    k_cvt<<<(NN * HH / 8) / 256, 256, 0, stream>>>(W1, (uint4*)W1h);
    k_build<<<NN, 256, 0, stream>>>(x, colfill, degX, degA, csrX, csrA, cscA);
    k_prep<<<NN / 256, 256, 0, stream>>>(colfill, batch, dinv, cnt);
    k_s<<<NN / 256, 256, 0, stream>>>(degA, csrA, dinv, batch, s);
    k_spmm1<<<dim3(NN / 2, NCH), 128, 0, stream>>>((const char*)W1h, degX, csrX, dinv, Mh);
    k_conv1<<<dim3(NN / 2, NCH), 128, 0, stream>>>((const char*)Mh, b1, dinv, colfill, cscA, hB);
    k_poolA<<<dim3(HH / 2048, PRG), 256, 0, stream>>>(hB, s, part);
    k_poolB<<<(GG * HH / 4) / 256, 256, 0, stream>>>(part, t);
    k_final<<<dim3(NN / 1024, FJG), 256, 0, stream>>>(W2, t, cnt, part2);
    k_fin2<<<(GG * NN / 4) / 256, 256, 0, stream>>>(part2, b2, out);
}